// Round 1
// baseline (6945.660 us; speedup 1.0000x reference)
//
#include <hip/hip_runtime.h>
#include <hip/hip_bf16.h>
#include <math.h>

#define S 2048
#define D 2048
#define NQ 32
#define NKV 8
#define HD 64
#define HALF 32
#define NREP 4   // NQ / NKV
#define KV_D (NKV * HD)   // 512

// ---------------------------------------------------------------------------
// Tiled fp32 GEMM: C[M,N] = A[M,K] @ B[K,N], all row-major.
// 256 threads, 32x32 tile, each thread computes 2x2 outputs.
// M, N, K assumed multiples of 32 (true here: 2048 / 512).
// ---------------------------------------------------------------------------
__global__ __launch_bounds__(256) void gemm_f32(const float* __restrict__ A,
                                                const float* __restrict__ B,
                                                float* __restrict__ C,
                                                int M, int N, int Kdim) {
    __shared__ float As[32][33];
    __shared__ float Bs[32][33];
    const int tx = threadIdx.x & 15;        // 0..15 -> col pair
    const int ty = threadIdx.x >> 4;        // 0..15 -> row pair
    const int bm = blockIdx.y * 32;
    const int bn = blockIdx.x * 32;

    float acc00 = 0.f, acc01 = 0.f, acc10 = 0.f, acc11 = 0.f;

    for (int k0 = 0; k0 < Kdim; k0 += 32) {
        for (int i = threadIdx.x; i < 32 * 32; i += 256) {
            int r = i >> 5, c = i & 31;
            As[r][c] = A[(size_t)(bm + r) * Kdim + (k0 + c)];
            Bs[r][c] = B[(size_t)(k0 + r) * N + (bn + c)];
        }
        __syncthreads();
        #pragma unroll
        for (int k = 0; k < 32; ++k) {
            float a0 = As[ty * 2 + 0][k];
            float a1 = As[ty * 2 + 1][k];
            float b0 = Bs[k][tx * 2 + 0];
            float b1 = Bs[k][tx * 2 + 1];
            acc00 = fmaf(a0, b0, acc00);
            acc01 = fmaf(a0, b1, acc01);
            acc10 = fmaf(a1, b0, acc10);
            acc11 = fmaf(a1, b1, acc11);
        }
        __syncthreads();
    }
    C[(size_t)(bm + ty * 2 + 0) * N + (bn + tx * 2 + 0)] = acc00;
    C[(size_t)(bm + ty * 2 + 0) * N + (bn + tx * 2 + 1)] = acc01;
    C[(size_t)(bm + ty * 2 + 1) * N + (bn + tx * 2 + 0)] = acc10;
    C[(size_t)(bm + ty * 2 + 1) * N + (bn + tx * 2 + 1)] = acc11;
}

// ---------------------------------------------------------------------------
// Fused RMSNorm (per head, HD=64) + RoPE, in place.
// grid = (S, NH), block = 64 (one wave). X layout: [S, NH*HD].
// cos/sin layout: [S, HALF].
// ---------------------------------------------------------------------------
__global__ __launch_bounds__(64) void rmsnorm_rope(float* __restrict__ X,
                                                   const float* __restrict__ g,
                                                   const float* __restrict__ cosT,
                                                   const float* __restrict__ sinT,
                                                   int NH) {
    const int s = blockIdx.x;
    const int h = blockIdx.y;
    const int d = threadIdx.x;  // 0..63
    float* xp = X + (size_t)s * (NH * HD) + (size_t)h * HD;

    float v = xp[d];
    float ss = v * v;
    #pragma unroll
    for (int off = 32; off > 0; off >>= 1) ss += __shfl_down(ss, off);
    ss = __shfl(ss, 0);
    float inv_denom = rsqrtf(ss * (1.0f / HD) + 1e-6f);
    float xn = v * inv_denom * g[d];

    // RoPE: pairs (i, i+32)
    float other = __shfl(xn, d ^ 32);
    float c = cosT[(size_t)s * HALF + (d & 31)];
    float sn = sinT[(size_t)s * HALF + (d & 31)];
    float outv;
    if (d < HALF) {
        outv = xn * c - other * sn;     // x1*c - x2*s
    } else {
        outv = other * sn + xn * c;     // x1*s + x2*c
    }
    xp[d] = outv;
}

// ---------------------------------------------------------------------------
// Causal GQA attention, one block of 256 threads per (query s, head h).
// Q: [S, NQ*HD], K/V: [S, NKV*HD], O: [S, NQ*HD].
// ---------------------------------------------------------------------------
__global__ __launch_bounds__(256) void attn_kernel(const float* __restrict__ Q,
                                                   const float* __restrict__ K,
                                                   const float* __restrict__ V,
                                                   float* __restrict__ O) {
    const int s = blockIdx.x;
    const int h = blockIdx.y;
    const int kvh = h / NREP;
    const int tid = threadIdx.x;
    const int lane = tid & 63;
    const int wid = tid >> 6;

    __shared__ float q[HD];
    __shared__ float sc[S];          // 8 KB, scores then probs
    __shared__ float redmax[4];
    __shared__ float redsum[4];
    __shared__ float ored[4][HD];

    if (tid < HD) q[tid] = Q[(size_t)s * D + (size_t)h * HD + tid];
    __syncthreads();

    const int L = s + 1;

    // ---- scores = (q . k_t) * scale for t in [0, L)
    const float scale = 0.125f;  // 1/sqrt(64)
    for (int t = tid; t < L; t += 256) {
        const float* kp = K + (size_t)t * KV_D + (size_t)kvh * HD;
        float acc = 0.f;
        #pragma unroll
        for (int d = 0; d < HD; ++d) acc = fmaf(q[d], kp[d], acc);
        sc[t] = acc * scale;
    }
    __syncthreads();

    // ---- block max
    float m = -INFINITY;
    for (int t = tid; t < L; t += 256) m = fmaxf(m, sc[t]);
    #pragma unroll
    for (int off = 32; off > 0; off >>= 1) m = fmaxf(m, __shfl_down(m, off));
    if (lane == 0) redmax[wid] = m;
    __syncthreads();
    m = fmaxf(fmaxf(redmax[0], redmax[1]), fmaxf(redmax[2], redmax[3]));

    // ---- exp + sum
    float lsum = 0.f;
    for (int t = tid; t < L; t += 256) {
        float e = __expf(sc[t] - m);
        sc[t] = e;
        lsum += e;
    }
    #pragma unroll
    for (int off = 32; off > 0; off >>= 1) lsum += __shfl_down(lsum, off);
    if (lane == 0) redsum[wid] = lsum;
    __syncthreads();
    const float inv_sum = 1.0f / (redsum[0] + redsum[1] + redsum[2] + redsum[3]);

    // ---- o[d] = sum_t p[t] * V[t, kvh*HD + d]
    const int d = tid & 63;
    const int quarter = tid >> 6;
    float o = 0.f;
    for (int t = quarter; t < L; t += 4) {
        o = fmaf(sc[t], V[(size_t)t * KV_D + (size_t)kvh * HD + d], o);
    }
    ored[quarter][d] = o;
    __syncthreads();
    if (quarter == 0) {
        float r = ored[0][d] + ored[1][d] + ored[2][d] + ored[3][d];
        O[(size_t)s * D + (size_t)h * HD + d] = r * inv_sum;
    }
}

// ---------------------------------------------------------------------------
extern "C" void kernel_launch(void* const* d_in, const int* in_sizes, int n_in,
                              void* d_out, int out_size, void* d_ws, size_t ws_size,
                              hipStream_t stream) {
    const float* x    = (const float*)d_in[0];
    const float* cosT = (const float*)d_in[1];
    const float* sinT = (const float*)d_in[2];
    const float* g_q  = (const float*)d_in[3];
    const float* g_k  = (const float*)d_in[4];
    const float* Wq   = (const float*)d_in[5];
    const float* Wk   = (const float*)d_in[6];
    const float* Wv   = (const float*)d_in[7];
    const float* Wo   = (const float*)d_in[8];
    float* out = (float*)d_out;

    float* ws = (float*)d_ws;
    float* Q  = ws;                                  // S*D      = 4M floats
    float* K  = Q + (size_t)S * D;                   // S*KV_D   = 1M floats
    float* V  = K + (size_t)S * KV_D;                // S*KV_D   = 1M floats
    float* O  = V + (size_t)S * KV_D;                // S*D      = 4M floats

    // QKV projections
    gemm_f32<<<dim3(D / 32, S / 32), 256, 0, stream>>>(x, Wq, Q, S, D, D);
    gemm_f32<<<dim3(KV_D / 32, S / 32), 256, 0, stream>>>(x, Wk, K, S, KV_D, D);
    gemm_f32<<<dim3(KV_D / 32, S / 32), 256, 0, stream>>>(x, Wv, V, S, KV_D, D);

    // RMSNorm + RoPE (in place)
    rmsnorm_rope<<<dim3(S, NQ), 64, 0, stream>>>(Q, g_q, cosT, sinT, NQ);
    rmsnorm_rope<<<dim3(S, NKV), 64, 0, stream>>>(K, g_k, cosT, sinT, NKV);

    // Causal GQA attention
    attn_kernel<<<dim3(S, NQ), 256, 0, stream>>>(Q, K, V, O);

    // Output projection
    gemm_f32<<<dim3(D / 32, S / 32), 256, 0, stream>>>(O, Wo, out, S, D, D);
}

// Round 2
// 1406.037 us; speedup vs baseline: 4.9399x; 4.9399x over previous
//
#include <hip/hip_runtime.h>
#include <hip/hip_bf16.h>
#include <math.h>

#define S 2048
#define D 2048
#define NQ 32
#define NKV 8
#define HD 64
#define HALF 32
#define NREP 4
#define KV_D (NKV * HD)   // 512

typedef float f4 __attribute__((ext_vector_type(4)));

// ---------------------------------------------------------------------------
// Tiled fp32 GEMM v2: C[M,N] = A[M,K] @ B[K,N], row-major.
// 64x64 tile, 256 threads, 4x4 outputs/thread, float4 LDS reads (A transposed).
// M,N,K multiples of 64.
// ---------------------------------------------------------------------------
#define GPAD 68
__global__ __launch_bounds__(256) void gemm_f32_v2(const float* __restrict__ A,
                                                   const float* __restrict__ B,
                                                   float* __restrict__ C,
                                                   int M, int N, int Kdim) {
    __shared__ float At[64][GPAD];   // At[k][i] (A transposed)
    __shared__ float Bs[64][GPAD];   // Bs[k][j]
    const int tid = threadIdx.x;
    const int tx = tid & 15;         // col group (4 cols)
    const int ty = tid >> 4;         // row group (4 rows)
    const int bm = blockIdx.y * 64;
    const int bn = blockIdx.x * 64;

    float acc[4][4];
    #pragma unroll
    for (int r = 0; r < 4; ++r)
        #pragma unroll
        for (int c = 0; c < 4; ++c) acc[r][c] = 0.f;

    for (int k0 = 0; k0 < Kdim; k0 += 64) {
        // stage: 64 rows x 16 float4 each for A and B; 4 per thread
        #pragma unroll
        for (int it = 0; it < 4; ++it) {
            int idx = tid + it * 256;
            int row = idx >> 4;            // 0..63
            int c4  = (idx & 15) * 4;      // 0..60
            f4 a = *(const f4*)&A[(size_t)(bm + row) * Kdim + (k0 + c4)];
            At[c4 + 0][row] = a[0];
            At[c4 + 1][row] = a[1];
            At[c4 + 2][row] = a[2];
            At[c4 + 3][row] = a[3];
            f4 b = *(const f4*)&B[(size_t)(k0 + row) * N + (bn + c4)];
            *(f4*)&Bs[row][c4] = b;
        }
        __syncthreads();

        #pragma unroll 8
        for (int k = 0; k < 64; ++k) {
            f4 av = *(const f4*)&At[k][4 * ty];
            f4 bv = *(const f4*)&Bs[k][4 * tx];
            #pragma unroll
            for (int r = 0; r < 4; ++r)
                #pragma unroll
                for (int c = 0; c < 4; ++c)
                    acc[r][c] = fmaf(av[r], bv[c], acc[r][c]);
        }
        __syncthreads();
    }
    #pragma unroll
    for (int r = 0; r < 4; ++r) {
        f4 o = {acc[r][0], acc[r][1], acc[r][2], acc[r][3]};
        *(f4*)&C[(size_t)(bm + 4 * ty + r) * N + (bn + 4 * tx)] = o;
    }
}

// ---------------------------------------------------------------------------
// Fused RMSNorm (per head, HD=64) + RoPE, in place. (unchanged from R1)
// ---------------------------------------------------------------------------
__global__ __launch_bounds__(64) void rmsnorm_rope(float* __restrict__ X,
                                                   const float* __restrict__ g,
                                                   const float* __restrict__ cosT,
                                                   const float* __restrict__ sinT,
                                                   int NH) {
    const int s = blockIdx.x;
    const int h = blockIdx.y;
    const int d = threadIdx.x;
    float* xp = X + (size_t)s * (NH * HD) + (size_t)h * HD;

    float v = xp[d];
    float ss = v * v;
    #pragma unroll
    for (int off = 32; off > 0; off >>= 1) ss += __shfl_down(ss, off);
    ss = __shfl(ss, 0);
    float inv_denom = rsqrtf(ss * (1.0f / HD) + 1e-6f);
    float xn = v * inv_denom * g[d];

    float other = __shfl(xn, d ^ 32);
    float c = cosT[(size_t)s * HALF + (d & 31)];
    float sn = sinT[(size_t)s * HALF + (d & 31)];
    float outv;
    if (d < HALF) outv = xn * c - other * sn;
    else          outv = other * sn + xn * c;
    xp[d] = outv;
}

// ---------------------------------------------------------------------------
// Flash-style causal GQA attention.
// grid = (S/64, NQ), block = 256. 64x64 tiles, 4x4 per thread, online softmax.
// Q,O: [S, NQ*HD]; K,V: [S, NKV*HD].
// ---------------------------------------------------------------------------
#define BQ 64
#define BK 64
#define APAD 68
__global__ __launch_bounds__(256) void flash_attn(const float* __restrict__ Q,
                                                  const float* __restrict__ K,
                                                  const float* __restrict__ V,
                                                  float* __restrict__ O) {
    __shared__ float Qt[HD][APAD];   // Qt[d][i]  (Q transposed, pre-scaled)
    __shared__ float Kt[HD][APAD];   // Kt[d][j]  (K transposed)
    __shared__ float Vs[BK][APAD];   // Vs[j][d]
    __shared__ float Ps[BQ][APAD];   // Ps[i][j]

    const int q0 = blockIdx.x * BQ;
    const int h = blockIdx.y;
    const int kvh = h / NREP;
    const int tid = threadIdx.x;
    const int tx = tid & 15;   // key/col group (4)
    const int ty = tid >> 4;   // query/row group (4)

    float acc[4][4];
    float m_i[4], l_i[4];
    #pragma unroll
    for (int r = 0; r < 4; ++r) {
        m_i[r] = -INFINITY;
        l_i[r] = 0.f;
        #pragma unroll
        for (int c = 0; c < 4; ++c) acc[r][c] = 0.f;
    }

    // Load Q tile transposed, pre-scaled by 1/sqrt(HD)
    #pragma unroll
    for (int it = 0; it < 4; ++it) {
        int idx = tid + it * 256;
        int i = idx >> 4;
        int d4 = (idx & 15) * 4;
        f4 qv = *(const f4*)&Q[(size_t)(q0 + i) * D + (size_t)h * HD + d4];
        Qt[d4 + 0][i] = qv[0] * 0.125f;
        Qt[d4 + 1][i] = qv[1] * 0.125f;
        Qt[d4 + 2][i] = qv[2] * 0.125f;
        Qt[d4 + 3][i] = qv[3] * 0.125f;
    }

    for (int t0 = 0; t0 <= q0; t0 += BK) {
        // stage K (transposed) and V
        #pragma unroll
        for (int it = 0; it < 4; ++it) {
            int idx = tid + it * 256;
            int j = idx >> 4;
            int d4 = (idx & 15) * 4;
            f4 kv = *(const f4*)&K[(size_t)(t0 + j) * KV_D + (size_t)kvh * HD + d4];
            Kt[d4 + 0][j] = kv[0];
            Kt[d4 + 1][j] = kv[1];
            Kt[d4 + 2][j] = kv[2];
            Kt[d4 + 3][j] = kv[3];
            f4 vv = *(const f4*)&V[(size_t)(t0 + j) * KV_D + (size_t)kvh * HD + d4];
            *(f4*)&Vs[j][d4] = vv;
        }
        __syncthreads();

        // ---- S = (Q*scale) . K^T  (4x4 per thread)
        float s[4][4];
        #pragma unroll
        for (int r = 0; r < 4; ++r)
            #pragma unroll
            for (int c = 0; c < 4; ++c) s[r][c] = 0.f;

        #pragma unroll 8
        for (int d = 0; d < HD; ++d) {
            f4 qv = *(const f4*)&Qt[d][4 * ty];
            f4 kv = *(const f4*)&Kt[d][4 * tx];
            #pragma unroll
            for (int r = 0; r < 4; ++r)
                #pragma unroll
                for (int c = 0; c < 4; ++c)
                    s[r][c] = fmaf(qv[r], kv[c], s[r][c]);
        }

        // ---- causal mask (diagonal tile only)
        if (t0 == q0) {
            #pragma unroll
            for (int r = 0; r < 4; ++r)
                #pragma unroll
                for (int c = 0; c < 4; ++c)
                    if (t0 + 4 * tx + c > q0 + 4 * ty + r) s[r][c] = -INFINITY;
        }

        // ---- online softmax update
        float p[4][4];
        #pragma unroll
        for (int r = 0; r < 4; ++r) {
            float mr = fmaxf(fmaxf(s[r][0], s[r][1]), fmaxf(s[r][2], s[r][3]));
            mr = fmaxf(mr, __shfl_xor(mr, 1));
            mr = fmaxf(mr, __shfl_xor(mr, 2));
            mr = fmaxf(mr, __shfl_xor(mr, 4));
            mr = fmaxf(mr, __shfl_xor(mr, 8));
            float m_new = fmaxf(m_i[r], mr);
            float alpha = __expf(m_i[r] - m_new);
            float rs = 0.f;
            #pragma unroll
            for (int c = 0; c < 4; ++c) {
                p[r][c] = __expf(s[r][c] - m_new);
                rs += p[r][c];
            }
            rs += __shfl_xor(rs, 1);
            rs += __shfl_xor(rs, 2);
            rs += __shfl_xor(rs, 4);
            rs += __shfl_xor(rs, 8);
            l_i[r] = l_i[r] * alpha + rs;
            m_i[r] = m_new;
            #pragma unroll
            for (int c = 0; c < 4; ++c) acc[r][c] *= alpha;
        }

        // ---- write P tile to LDS
        #pragma unroll
        for (int r = 0; r < 4; ++r) {
            f4 pv = {p[r][0], p[r][1], p[r][2], p[r][3]};
            *(f4*)&Ps[4 * ty + r][4 * tx] = pv;
        }
        __syncthreads();

        // ---- O += P . V
        #pragma unroll 4
        for (int j0 = 0; j0 < BK; j0 += 4) {
            f4 vv0 = *(const f4*)&Vs[j0 + 0][4 * tx];
            f4 vv1 = *(const f4*)&Vs[j0 + 1][4 * tx];
            f4 vv2 = *(const f4*)&Vs[j0 + 2][4 * tx];
            f4 vv3 = *(const f4*)&Vs[j0 + 3][4 * tx];
            #pragma unroll
            for (int r = 0; r < 4; ++r) {
                f4 pr = *(const f4*)&Ps[4 * ty + r][j0];
                #pragma unroll
                for (int c = 0; c < 4; ++c) {
                    float t = fmaf(pr[0], vv0[c], fmaf(pr[1], vv1[c],
                              fmaf(pr[2], vv2[c], pr[3] * vv3[c])));
                    acc[r][c] += t;
                }
            }
        }
        __syncthreads();   // before next-iter restage of Kt/Vs/Ps
    }

    // ---- epilogue: normalize and store
    #pragma unroll
    for (int r = 0; r < 4; ++r) {
        float inv_l = 1.0f / l_i[r];
        f4 o = {acc[r][0] * inv_l, acc[r][1] * inv_l,
                acc[r][2] * inv_l, acc[r][3] * inv_l};
        *(f4*)&O[(size_t)(q0 + 4 * ty + r) * D + (size_t)h * HD + 4 * tx] = o;
    }
}

// ---------------------------------------------------------------------------
extern "C" void kernel_launch(void* const* d_in, const int* in_sizes, int n_in,
                              void* d_out, int out_size, void* d_ws, size_t ws_size,
                              hipStream_t stream) {
    const float* x    = (const float*)d_in[0];
    const float* cosT = (const float*)d_in[1];
    const float* sinT = (const float*)d_in[2];
    const float* g_q  = (const float*)d_in[3];
    const float* g_k  = (const float*)d_in[4];
    const float* Wq   = (const float*)d_in[5];
    const float* Wk   = (const float*)d_in[6];
    const float* Wv   = (const float*)d_in[7];
    const float* Wo   = (const float*)d_in[8];
    float* out = (float*)d_out;

    float* ws = (float*)d_ws;
    float* Q  = ws;                                  // S*D
    float* K  = Q + (size_t)S * D;                   // S*KV_D
    float* V  = K + (size_t)S * KV_D;                // S*KV_D
    float* O  = V + (size_t)S * KV_D;                // S*D

    // QKV projections
    gemm_f32_v2<<<dim3(D / 64, S / 64), 256, 0, stream>>>(x, Wq, Q, S, D, D);
    gemm_f32_v2<<<dim3(KV_D / 64, S / 64), 256, 0, stream>>>(x, Wk, K, S, KV_D, D);
    gemm_f32_v2<<<dim3(KV_D / 64, S / 64), 256, 0, stream>>>(x, Wv, V, S, KV_D, D);

    // RMSNorm + RoPE (in place)
    rmsnorm_rope<<<dim3(S, NQ), 64, 0, stream>>>(Q, g_q, cosT, sinT, NQ);
    rmsnorm_rope<<<dim3(S, NKV), 64, 0, stream>>>(K, g_k, cosT, sinT, NKV);

    // Flash causal GQA attention
    flash_attn<<<dim3(S / BQ, NQ), 256, 0, stream>>>(Q, K, V, O);

    // Output projection
    gemm_f32_v2<<<dim3(D / 64, S / 64), 256, 0, stream>>>(O, Wo, out, S, D, D);
}

// Round 3
// 408.237 us; speedup vs baseline: 17.0138x; 3.4442x over previous
//
#include <hip/hip_runtime.h>
#include <hip/hip_bf16.h>
#include <math.h>

#define S 2048
#define D 2048
#define NQ 32
#define NKV 8
#define HD 64
#define HALF 32
#define NREP 4
#define QKV_N 3072           // NQ*HD + 2*NKV*HD
#define KCOL 2048            // K starts here in fused QKV buffer
#define VCOL 2560            // V starts here

typedef unsigned short ushort_t;
typedef __attribute__((ext_vector_type(8))) short bf16x8;   // 8 bf16 = 4 VGPRs
typedef __attribute__((ext_vector_type(4))) float f32x4;
typedef float f4 __attribute__((ext_vector_type(4)));

__device__ __forceinline__ ushort_t f2bf(float f) {
    __hip_bfloat16 h = __float2bfloat16(f);
    return *reinterpret_cast<ushort_t*>(&h);
}
__device__ __forceinline__ float bf2f(ushort_t u) {
    __hip_bfloat16 h = *reinterpret_cast<__hip_bfloat16*>(&u);
    return __bfloat162float(h);
}

// async 16B global -> LDS (lds base must be wave-uniform; HW scatters lane*16)
__device__ __forceinline__ void load_lds16(const ushort_t* g, ushort_t* l) {
    __builtin_amdgcn_global_load_lds(
        (const __attribute__((address_space(1))) unsigned int*)g,
        (__attribute__((address_space(3))) unsigned int*)l,
        16, 0, 0);
}

// ---------------------------------------------------------------------------
// fp32 -> bf16 elementwise convert
// ---------------------------------------------------------------------------
__global__ __launch_bounds__(256) void convert_bf16(const float* __restrict__ src,
                                                    ushort_t* __restrict__ dst, int n) {
    int i = (blockIdx.x * 256 + threadIdx.x) * 4;
    if (i + 3 < n) {
        f4 v = *(const f4*)&src[i];
        dst[i + 0] = f2bf(v[0]);
        dst[i + 1] = f2bf(v[1]);
        dst[i + 2] = f2bf(v[2]);
        dst[i + 3] = f2bf(v[3]);
    }
}

// ---------------------------------------------------------------------------
// Transposing convert: dst[(row_off+n)*pitch + k] = bf16(src[k*N + n])
// block 256 = 32x8, grid (N/32, K/32)
// ---------------------------------------------------------------------------
__global__ __launch_bounds__(256) void transpose_w(const float* __restrict__ src,
                                                   ushort_t* __restrict__ dst,
                                                   int Kdim, int N, int pitch, int row_off) {
    __shared__ float tile[32][33];
    const int n0 = blockIdx.x * 32, k0 = blockIdx.y * 32;
    const int tx = threadIdx.x & 31, ty = threadIdx.x >> 5;   // ty 0..7
    #pragma unroll
    for (int i = 0; i < 32; i += 8)
        tile[ty + i][tx] = src[(size_t)(k0 + ty + i) * N + (n0 + tx)];
    __syncthreads();
    #pragma unroll
    for (int i = 0; i < 32; i += 8)
        dst[(size_t)(row_off + n0 + ty + i) * pitch + (k0 + tx)] = f2bf(tile[tx][ty + i]);
}

// ---------------------------------------------------------------------------
// bf16 MFMA GEMM (m97 structure): C[M,N] = A[M,K] @ BT[N,K]^T
// 256 thr = 4 waves, 128x128 tile, BK=32, global_load_lds(16B) staging.
// ---------------------------------------------------------------------------
template <typename OutT>
__global__ __launch_bounds__(256) void gemm_bt(const ushort_t* __restrict__ A,
                                               const ushort_t* __restrict__ BT,
                                               OutT* __restrict__ C,
                                               int M, int N, int Kdim) {
    __shared__ ushort_t As[128][32];   // [row][k], pitch 64B (global_load_lds order)
    __shared__ ushort_t Bs[128][32];
    const int tid = threadIdx.x;
    const int w = tid >> 6, lane = tid & 63;
    const int r16 = lane & 15, quad = lane >> 4;
    const int wm = (w >> 1) * 64, wn = (w & 1) * 64;
    const int bm = blockIdx.y * 128, bn = blockIdx.x * 128;
    const int sr = lane >> 2;            // staging row within 16-row chunk
    const int sc8 = (lane & 3) * 8;      // staging col (ushort units)

    f32x4 acc[4][4];
    #pragma unroll
    for (int r = 0; r < 4; ++r)
        #pragma unroll
        for (int c = 0; c < 4; ++c) acc[r][c] = (f32x4){0.f, 0.f, 0.f, 0.f};

    for (int k0 = 0; k0 < Kdim; k0 += 32) {
        __syncthreads();
        #pragma unroll
        for (int i = 0; i < 2; ++i) {
            int rowt = w * 32 + i * 16;
            load_lds16(A  + (size_t)(bm + rowt + sr) * Kdim + k0 + sc8, &As[rowt][0]);
            load_lds16(BT + (size_t)(bn + rowt + sr) * Kdim + k0 + sc8, &Bs[rowt][0]);
        }
        __syncthreads();

        bf16x8 af[4], bfr[4];
        #pragma unroll
        for (int r = 0; r < 4; ++r) af[r]  = *(const bf16x8*)&As[wm + 16 * r + r16][quad * 8];
        #pragma unroll
        for (int c = 0; c < 4; ++c) bfr[c] = *(const bf16x8*)&Bs[wn + 16 * c + r16][quad * 8];
        #pragma unroll
        for (int r = 0; r < 4; ++r)
            #pragma unroll
            for (int c = 0; c < 4; ++c)
                acc[r][c] = __builtin_amdgcn_mfma_f32_16x16x32_bf16(af[r], bfr[c], acc[r][c], 0, 0, 0);
    }

    #pragma unroll
    for (int r = 0; r < 4; ++r)
        #pragma unroll
        for (int c = 0; c < 4; ++c)
            #pragma unroll
            for (int reg = 0; reg < 4; ++reg) {
                int row = bm + wm + 16 * r + quad * 4 + reg;
                int col = bn + wn + 16 * c + r16;
                float v = acc[r][c][reg];
                if constexpr (sizeof(OutT) == 2) C[(size_t)row * N + col] = (OutT)f2bf(v);
                else                             C[(size_t)row * N + col] = (OutT)v;
            }
}

// ---------------------------------------------------------------------------
// RMSNorm + RoPE on the fused QKV bf16 buffer (Q and K parts only), in place.
// grid (S, 10), block 256 = 4 waves, one head per wave (40 heads: 32 Q + 8 K).
// ---------------------------------------------------------------------------
__global__ __launch_bounds__(256) void rmsnorm_rope_b(ushort_t* __restrict__ QKV,
                                                      const float* __restrict__ gq,
                                                      const float* __restrict__ gk,
                                                      const float* __restrict__ cosT,
                                                      const float* __restrict__ sinT) {
    const int s = blockIdx.x;
    const int w = threadIdx.x >> 6;
    const int hh = blockIdx.y * 4 + w;         // 0..39
    const int d = threadIdx.x & 63;
    const float* g;
    int col;
    if (hh < NQ) { g = gq; col = hh * HD; }
    else         { g = gk; col = KCOL + (hh - NQ) * HD; }

    ushort_t* xp = QKV + (size_t)s * QKV_N + col;
    float v = bf2f(xp[d]);
    float ss = v * v;
    #pragma unroll
    for (int off = 32; off > 0; off >>= 1) ss += __shfl_down(ss, off);
    ss = __shfl(ss, 0);
    float inv = rsqrtf(ss * (1.0f / HD) + 1e-6f);
    float xn = v * inv * g[d];

    float other = __shfl(xn, d ^ 32);
    float c = cosT[(size_t)s * HALF + (d & 31)];
    float sn = sinT[(size_t)s * HALF + (d & 31)];
    float outv = (d < HALF) ? (xn * c - other * sn) : (other * sn + xn * c);
    xp[d] = f2bf(outv);
}

// ---------------------------------------------------------------------------
// MFMA flash attention (causal GQA). grid (S/64, NQ), block 256 = 4 waves.
// Wave w owns q rows [q0+16w, q0+16w+16). QKV fused bf16 [S, 3072]; O bf16 [S, 2048].
// ---------------------------------------------------------------------------
#define KP 36    // Ks/Vt/Ps row pitch in ushorts = 72 (144B, 16B-aligned, bank-spread)
__global__ __launch_bounds__(256) void flash_attn_mfma(const ushort_t* __restrict__ QKV,
                                                       ushort_t* __restrict__ O) {
    __shared__ ushort_t Ks[64][2 * KP];        // [key][hd]
    __shared__ ushort_t Vt[64][2 * KP];        // [hd][key]  (transposed)
    __shared__ ushort_t Ps[4][16][2 * KP];     // per wave: [row][key]

    const int q0 = blockIdx.x * 64;
    const int h  = blockIdx.y;
    const int kvh = h >> 2;
    const int tid = threadIdx.x;
    const int w = tid >> 6, lane = tid & 63;
    const int r16 = lane & 15, quad = lane >> 4;

    const int kcol = KCOL + kvh * HD;
    const int vcol = VCOL + kvh * HD;

    // Q fragments straight from global (A-layout: m=lane&15, k=quad*8+j)
    const ushort_t* qrow = QKV + (size_t)(q0 + 16 * w + r16) * QKV_N + h * HD;
    bf16x8 qf0 = *(const bf16x8*)(qrow + quad * 8);
    bf16x8 qf1 = *(const bf16x8*)(qrow + quad * 8 + 32);

    f32x4 accO[4];
    float m_i[4], l_i[4];
    #pragma unroll
    for (int c = 0; c < 4; ++c) accO[c] = (f32x4){0.f, 0.f, 0.f, 0.f};
    #pragma unroll
    for (int r = 0; r < 4; ++r) { m_i[r] = -INFINITY; l_i[r] = 0.f; }

    const int ntiles = blockIdx.x + 1;
    for (int t = 0; t < ntiles; ++t) {
        const int t0 = t * 64;
        __syncthreads();   // all waves done reading Ks/Vt of previous tile
        // ---- stage K tile [key][hd] and V tile transposed [hd][key]
        #pragma unroll
        for (int it = 0; it < 2; ++it) {
            int idx = tid + it * 256;
            int key = idx >> 3;            // 0..63
            int a   = idx & 7;
            int d8  = a * 8;
            const ushort_t* krow = QKV + (size_t)(t0 + key) * QKV_N;
            bf16x8 kv = *(const bf16x8*)(krow + kcol + d8);
            *(bf16x8*)&Ks[key][d8] = kv;
            bf16x8 vv = *(const bf16x8*)(krow + vcol + d8);
            #pragma unroll
            for (int j = 0; j < 8; ++j) {
                int jj = (j + a) & 7;      // bank-rotation: avoids 8-way write conflict
                Vt[d8 + jj][key] = ((const ushort_t*)&vv)[jj];
            }
        }
        __syncthreads();

        // ---- S = Q K^T (B-frag: n=key=lane&15, k=hd=quad*8+j)
        f32x4 sc[4];
        #pragma unroll
        for (int c = 0; c < 4; ++c) {
            bf16x8 kf0 = *(const bf16x8*)&Ks[16 * c + r16][quad * 8];
            bf16x8 kf1 = *(const bf16x8*)&Ks[16 * c + r16][quad * 8 + 32];
            f32x4 z = (f32x4){0.f, 0.f, 0.f, 0.f};
            z = __builtin_amdgcn_mfma_f32_16x16x32_bf16(qf0, kf0, z, 0, 0, 0);
            z = __builtin_amdgcn_mfma_f32_16x16x32_bf16(qf1, kf1, z, 0, 0, 0);
            sc[c] = z;
        }

        // ---- scale + causal mask (diagonal tile only)
        float sv[4][4];   // [c][reg]
        const bool diag = (t0 == q0);
        #pragma unroll
        for (int c = 0; c < 4; ++c)
            #pragma unroll
            for (int reg = 0; reg < 4; ++reg) {
                float v = sc[c][reg] * 0.125f;
                if (diag) {
                    int colg = t0 + 16 * c + r16;
                    int rowg = q0 + 16 * w + quad * 4 + reg;
                    if (colg > rowg) v = -INFINITY;
                }
                sv[c][reg] = v;
            }

        // ---- online softmax (rows live across 16 lanes of each quad)
        #pragma unroll
        for (int reg = 0; reg < 4; ++reg) {
            float mx = fmaxf(fmaxf(sv[0][reg], sv[1][reg]), fmaxf(sv[2][reg], sv[3][reg]));
            mx = fmaxf(mx, __shfl_xor(mx, 1));
            mx = fmaxf(mx, __shfl_xor(mx, 2));
            mx = fmaxf(mx, __shfl_xor(mx, 4));
            mx = fmaxf(mx, __shfl_xor(mx, 8));
            float mnew = fmaxf(m_i[reg], mx);
            float alpha = __expf(m_i[reg] - mnew);
            float rs = 0.f;
            #pragma unroll
            for (int c = 0; c < 4; ++c) {
                float p = __expf(sv[c][reg] - mnew);
                Ps[w][quad * 4 + reg][16 * c + r16] = f2bf(p);   // C-layout -> [row][key]
                rs += p;
            }
            rs += __shfl_xor(rs, 1);
            rs += __shfl_xor(rs, 2);
            rs += __shfl_xor(rs, 4);
            rs += __shfl_xor(rs, 8);
            l_i[reg] = l_i[reg] * alpha + rs;
            m_i[reg] = mnew;
            #pragma unroll
            for (int c = 0; c < 4; ++c) accO[c][reg] *= alpha;
        }

        // ---- O += P V   (wave-local Ps round-trip; no barrier needed)
        bf16x8 pf0 = *(const bf16x8*)&Ps[w][r16][quad * 8];
        bf16x8 pf1 = *(const bf16x8*)&Ps[w][r16][quad * 8 + 32];
        #pragma unroll
        for (int c = 0; c < 4; ++c) {
            bf16x8 vf0 = *(const bf16x8*)&Vt[16 * c + r16][quad * 8];
            bf16x8 vf1 = *(const bf16x8*)&Vt[16 * c + r16][quad * 8 + 32];
            accO[c] = __builtin_amdgcn_mfma_f32_16x16x32_bf16(pf0, vf0, accO[c], 0, 0, 0);
            accO[c] = __builtin_amdgcn_mfma_f32_16x16x32_bf16(pf1, vf1, accO[c], 0, 0, 0);
        }
    }

    // ---- epilogue
    #pragma unroll
    for (int c = 0; c < 4; ++c)
        #pragma unroll
        for (int reg = 0; reg < 4; ++reg) {
            int row = q0 + 16 * w + quad * 4 + reg;
            float inv_l = 1.0f / l_i[reg];
            O[(size_t)row * D + h * HD + 16 * c + r16] = f2bf(accO[c][reg] * inv_l);
        }
}

// ---------------------------------------------------------------------------
extern "C" void kernel_launch(void* const* d_in, const int* in_sizes, int n_in,
                              void* d_out, int out_size, void* d_ws, size_t ws_size,
                              hipStream_t stream) {
    const float* x    = (const float*)d_in[0];
    const float* cosT = (const float*)d_in[1];
    const float* sinT = (const float*)d_in[2];
    const float* g_q  = (const float*)d_in[3];
    const float* g_k  = (const float*)d_in[4];
    const float* Wq   = (const float*)d_in[5];
    const float* Wk   = (const float*)d_in[6];
    const float* Wv   = (const float*)d_in[7];
    const float* Wo   = (const float*)d_in[8];
    float* out = (float*)d_out;

    char* base = (char*)d_ws;
    ushort_t* Xb    = (ushort_t*)base;                              // 8,388,608 B
    ushort_t* WqkvT = (ushort_t*)(base + 8388608);                  // 12,582,912 B
    ushort_t* QKVb  = (ushort_t*)(base + 8388608 + 12582912);       // 12,582,912 B
    ushort_t* WoT   = WqkvT;   // alias: Wo transpose happens after QKV GEMM
    ushort_t* Ob    = Xb;      // alias: attention output after Xb is dead

    // 1. convert x to bf16
    convert_bf16<<<(S * D) / 1024, 256, 0, stream>>>(x, Xb, S * D);
    // 2. transpose-convert Wq|Wk|Wv into fused [3072, 2048] bf16
    transpose_w<<<dim3(2048 / 32, 2048 / 32), 256, 0, stream>>>(Wq, WqkvT, 2048, 2048, 2048, 0);
    transpose_w<<<dim3(512 / 32, 2048 / 32), 256, 0, stream>>>(Wk, WqkvT, 2048, 512, 2048, 2048);
    transpose_w<<<dim3(512 / 32, 2048 / 32), 256, 0, stream>>>(Wv, WqkvT, 2048, 512, 2048, 2560);
    // 3. fused QKV projection (bf16 out)
    gemm_bt<ushort_t><<<dim3(QKV_N / 128, S / 128), 256, 0, stream>>>(Xb, WqkvT, QKVb, S, QKV_N, D);
    // 4. RMSNorm + RoPE on Q,K parts
    rmsnorm_rope_b<<<dim3(S, 10), 256, 0, stream>>>(QKVb, g_q, g_k, cosT, sinT);
    // 5. transpose Wo (into the now-dead WqkvT space)
    transpose_w<<<dim3(2048 / 32, 2048 / 32), 256, 0, stream>>>(Wo, WoT, 2048, 2048, 2048, 0);
    // 6. MFMA flash attention
    flash_attn_mfma<<<dim3(S / 64, NQ), 256, 0, stream>>>(QKVb, Ob);
    // 7. output projection (fp32 out)
    gemm_bt<float><<<dim3(D / 128, S / 128), 256, 0, stream>>>(Ob, WoT, out, S, D, D);
}

// Round 5
// 310.548 us; speedup vs baseline: 22.3658x; 1.3146x over previous
//
#include <hip/hip_runtime.h>
#include <hip/hip_bf16.h>
#include <math.h>

#define S 2048
#define D 2048
#define NQ 32
#define NKV 8
#define HD 64
#define HALF 32
#define NREP 4
#define QKV_N 3072           // NQ*HD + 2*NKV*HD
#define KCOL 2048            // K starts here in fused QKV buffer
#define VCOL 2560            // V starts here

typedef unsigned short ushort_t;
typedef __attribute__((ext_vector_type(8))) short bf16x8;   // 8 bf16 = 4 VGPRs
typedef __attribute__((ext_vector_type(4))) float f32x4;
typedef float f4 __attribute__((ext_vector_type(4)));

__device__ __forceinline__ ushort_t f2bf(float f) {
    __hip_bfloat16 h = __float2bfloat16(f);
    return *reinterpret_cast<ushort_t*>(&h);
}
__device__ __forceinline__ float bf2f(ushort_t u) {
    __hip_bfloat16 h = *reinterpret_cast<__hip_bfloat16*>(&u);
    return __bfloat162float(h);
}

// async 16B global -> LDS (LDS base wave-uniform; HW scatters lane*16; the
// GLOBAL address is per-lane, so swizzles go on the global side)
__device__ __forceinline__ void load_lds16(const ushort_t* g, ushort_t* l) {
    __builtin_amdgcn_global_load_lds(
        (const __attribute__((address_space(1))) unsigned int*)g,
        (__attribute__((address_space(3))) unsigned int*)l,
        16, 0, 0);
}

// ---------------------------------------------------------------------------
// fp32 -> bf16 elementwise convert
// ---------------------------------------------------------------------------
__global__ __launch_bounds__(256) void convert_bf16(const float* __restrict__ src,
                                                    ushort_t* __restrict__ dst, int n) {
    int i = (blockIdx.x * 256 + threadIdx.x) * 4;
    if (i + 3 < n) {
        f4 v = *(const f4*)&src[i];
        dst[i + 0] = f2bf(v[0]);
        dst[i + 1] = f2bf(v[1]);
        dst[i + 2] = f2bf(v[2]);
        dst[i + 3] = f2bf(v[3]);
    }
}

// ---------------------------------------------------------------------------
// Transposing convert (fp32 -> bf16): dst[(row_off+n)*pitch + k] = src[k*N + n]
// ---------------------------------------------------------------------------
__global__ __launch_bounds__(256) void transpose_w(const float* __restrict__ src,
                                                   ushort_t* __restrict__ dst,
                                                   int Kdim, int N, int pitch, int row_off) {
    __shared__ float tile[32][33];
    const int n0 = blockIdx.x * 32, k0 = blockIdx.y * 32;
    const int tx = threadIdx.x & 31, ty = threadIdx.x >> 5;
    #pragma unroll
    for (int i = 0; i < 32; i += 8)
        tile[ty + i][tx] = src[(size_t)(k0 + ty + i) * N + (n0 + tx)];
    __syncthreads();
    #pragma unroll
    for (int i = 0; i < 32; i += 8)
        dst[(size_t)(row_off + n0 + ty + i) * pitch + (k0 + tx)] = f2bf(tile[tx][ty + i]);
}

// ---------------------------------------------------------------------------
// bf16 transpose of the V part of QKV: VTg[d][s] = QKV[s][VCOL + d]
// grid (S/32, 512/32), block 256 = 32x8
// ---------------------------------------------------------------------------
__global__ __launch_bounds__(256) void transpose_v(const ushort_t* __restrict__ src,
                                                   ushort_t* __restrict__ dst) {
    __shared__ ushort_t tile[32][33];
    const int s0 = blockIdx.x * 32, d0 = blockIdx.y * 32;
    const int tx = threadIdx.x & 31, ty = threadIdx.x >> 5;
    #pragma unroll
    for (int i = 0; i < 32; i += 8)
        tile[ty + i][tx] = src[(size_t)(s0 + ty + i) * QKV_N + VCOL + d0 + tx];
    __syncthreads();
    #pragma unroll
    for (int i = 0; i < 32; i += 8)
        dst[(size_t)(d0 + ty + i) * S + s0 + tx] = tile[tx][ty + i];
}

// ---------------------------------------------------------------------------
// bf16 MFMA GEMM (m97 structure): C[M,N] = A[M,K] @ BT[N,K]^T
// 256 thr = 4 waves, 128x128 tile, BK=32, global_load_lds(16B) staging.
// ---------------------------------------------------------------------------
template <typename OutT>
__global__ __launch_bounds__(256) void gemm_bt(const ushort_t* __restrict__ A,
                                               const ushort_t* __restrict__ BT,
                                               OutT* __restrict__ C,
                                               int M, int N, int Kdim) {
    __shared__ ushort_t As[128][32];
    __shared__ ushort_t Bs[128][32];
    const int tid = threadIdx.x;
    const int w = tid >> 6, lane = tid & 63;
    const int r16 = lane & 15, quad = lane >> 4;
    const int wm = (w >> 1) * 64, wn = (w & 1) * 64;
    const int bm = blockIdx.y * 128, bn = blockIdx.x * 128;
    const int sr = lane >> 2;
    const int sc8 = (lane & 3) * 8;

    f32x4 acc[4][4];
    #pragma unroll
    for (int r = 0; r < 4; ++r)
        #pragma unroll
        for (int c = 0; c < 4; ++c) acc[r][c] = (f32x4){0.f, 0.f, 0.f, 0.f};

    for (int k0 = 0; k0 < Kdim; k0 += 32) {
        __syncthreads();
        #pragma unroll
        for (int i = 0; i < 2; ++i) {
            int rowt = w * 32 + i * 16;
            load_lds16(A  + (size_t)(bm + rowt + sr) * Kdim + k0 + sc8, &As[rowt][0]);
            load_lds16(BT + (size_t)(bn + rowt + sr) * Kdim + k0 + sc8, &Bs[rowt][0]);
        }
        __syncthreads();

        bf16x8 af[4], bfr[4];
        #pragma unroll
        for (int r = 0; r < 4; ++r) af[r]  = *(const bf16x8*)&As[wm + 16 * r + r16][quad * 8];
        #pragma unroll
        for (int c = 0; c < 4; ++c) bfr[c] = *(const bf16x8*)&Bs[wn + 16 * c + r16][quad * 8];
        #pragma unroll
        for (int r = 0; r < 4; ++r)
            #pragma unroll
            for (int c = 0; c < 4; ++c)
                acc[r][c] = __builtin_amdgcn_mfma_f32_16x16x32_bf16(af[r], bfr[c], acc[r][c], 0, 0, 0);
    }

    #pragma unroll
    for (int r = 0; r < 4; ++r)
        #pragma unroll
        for (int c = 0; c < 4; ++c)
            #pragma unroll
            for (int reg = 0; reg < 4; ++reg) {
                int row = bm + wm + 16 * r + quad * 4 + reg;
                int col = bn + wn + 16 * c + r16;
                float v = acc[r][c][reg];
                if constexpr (sizeof(OutT) == 2) C[(size_t)row * N + col] = (OutT)f2bf(v);
                else                             C[(size_t)row * N + col] = (OutT)v;
            }
}

// ---------------------------------------------------------------------------
// RMSNorm + RoPE on the fused QKV bf16 buffer (Q and K parts only), in place.
// ---------------------------------------------------------------------------
__global__ __launch_bounds__(256) void rmsnorm_rope_b(ushort_t* __restrict__ QKV,
                                                      const float* __restrict__ gq,
                                                      const float* __restrict__ gk,
                                                      const float* __restrict__ cosT,
                                                      const float* __restrict__ sinT) {
    const int s = blockIdx.x;
    const int w = threadIdx.x >> 6;
    const int hh = blockIdx.y * 4 + w;
    const int d = threadIdx.x & 63;
    const float* g;
    int col;
    if (hh < NQ) { g = gq; col = hh * HD; }
    else         { g = gk; col = KCOL + (hh - NQ) * HD; }

    ushort_t* xp = QKV + (size_t)s * QKV_N + col;
    float v = bf2f(xp[d]);
    float ss = v * v;
    #pragma unroll
    for (int off = 32; off > 0; off >>= 1) ss += __shfl_down(ss, off);
    ss = __shfl(ss, 0);
    float inv = rsqrtf(ss * (1.0f / HD) + 1e-6f);
    float xn = v * inv * g[d];

    float other = __shfl(xn, d ^ 32);
    float c = cosT[(size_t)s * HALF + (d & 31)];
    float sn = sinT[(size_t)s * HALF + (d & 31)];
    float outv = (d < HALF) ? (xn * c - other * sn) : (other * sn + xn * c);
    xp[d] = f2bf(outv);
}

// ---------------------------------------------------------------------------
// MFMA flash attention v2 (causal GQA). grid (S/64, NQ), block 256 = 4 waves.
// Static-max softmax (RMSNorm bounds |s| <= 8 -> exp2 arg <= 11.6, safe),
// l via MFMA ones-trick, K and V^T staged with global_load_lds (XOR-swizzled
// global addresses), double-buffered single-barrier prefetch loop.
// ---------------------------------------------------------------------------
__global__ __launch_bounds__(256) void flash_attn_mfma(const ushort_t* __restrict__ QKV,
                                                       const ushort_t* __restrict__ VTg,
                                                       ushort_t* __restrict__ O) {
    __shared__ ushort_t Ks[2][64][64];   // [buf][key][hd], 16B chunks XOR-swizzled
    __shared__ ushort_t Vt[2][64][64];   // [buf][hd][key]
    __shared__ ushort_t Ps[4][16][72];   // per-wave [row][key], 144B pitch (16B-aligned)

    const int qt = gridDim.x - 1 - blockIdx.x;   // longest causal chains first
    const int q0 = qt * 64;
    const int h  = blockIdx.y;
    const int kvh = h >> 2;
    const int tid = threadIdx.x;
    const int w = tid >> 6, lane = tid & 63;
    const int r16 = lane & 15, quad = lane >> 4;
    const int kcol = KCOL + kvh * HD;
    const int vtrow0 = kvh * HD;
    const int rsub = lane >> 3;          // staging: row within 8-row chunk
    const int jlog = (lane & 7) ^ rsub;  // staging: logical 16B chunk (XOR swizzle)
    const int rx = r16 & 7;              // read-side swizzle key

    // Q fragments (A-layout), prescaled by 1/sqrt(HD) * log2(e)
    const ushort_t* qrow = QKV + (size_t)(q0 + 16 * w + r16) * QKV_N + h * HD;
    bf16x8 qf0, qf1;
    {
        bf16x8 r0 = *(const bf16x8*)(qrow + quad * 8);
        bf16x8 r1 = *(const bf16x8*)(qrow + quad * 8 + 32);
        #pragma unroll
        for (int j = 0; j < 8; ++j) {
            qf0[j] = (short)f2bf(bf2f((ushort_t)r0[j]) * 0.18033688f);
            qf1[j] = (short)f2bf(bf2f((ushort_t)r1[j]) * 0.18033688f);
        }
    }

    // ones B-fragment for row-sum MFMA: B[k][n] = (n==0)
    bf16x8 onesf;
    {
        ushort_t ov = (r16 == 0) ? (ushort_t)0x3F80 : (ushort_t)0;
        #pragma unroll
        for (int j = 0; j < 8; ++j) onesf[j] = (short)ov;
    }

    f32x4 accO[4];
    f32x4 accL = (f32x4){0.f, 0.f, 0.f, 0.f};
    #pragma unroll
    for (int c = 0; c < 4; ++c) accO[c] = (f32x4){0.f, 0.f, 0.f, 0.f};

    auto stage = [&](int b, int t0) {
        #pragma unroll
        for (int i = 0; i < 2; ++i) {
            int base = w * 16 + i * 8;
            int row = base + rsub;
            load_lds16(QKV + (size_t)(t0 + row) * QKV_N + kcol + jlog * 8, &Ks[b][base][0]);
            load_lds16(VTg + (size_t)(vtrow0 + row) * S + t0 + jlog * 8, &Vt[b][base][0]);
        }
    };

    const int ntiles = qt + 1;
    stage(0, 0);

    for (int t = 0; t < ntiles; ++t) {
        __syncthreads();                          // buf[t&1] ready; buf[(t+1)&1] free
        if (t + 1 < ntiles) stage((t + 1) & 1, (t + 1) * 64);   // async prefetch

        const ushort_t (*K_)[64] = Ks[t & 1];
        const ushort_t (*V_)[64] = Vt[t & 1];
        const bool diag = (t == qt);

        // ---- S = Qs K^T
        f32x4 sc[4];
        #pragma unroll
        for (int c = 0; c < 4; ++c) {
            bf16x8 kf0 = *(const bf16x8*)&K_[16 * c + r16][(quad ^ rx) * 8];
            bf16x8 kf1 = *(const bf16x8*)&K_[16 * c + r16][((quad + 4) ^ rx) * 8];
            f32x4 z = (f32x4){0.f, 0.f, 0.f, 0.f};
            z = __builtin_amdgcn_mfma_f32_16x16x32_bf16(qf0, kf0, z, 0, 0, 0);
            z = __builtin_amdgcn_mfma_f32_16x16x32_bf16(qf1, kf1, z, 0, 0, 0);
            sc[c] = z;
        }

        // ---- p = exp2(s), causal mask on diagonal tile, store to Ps (C->A layout)
        #pragma unroll
        for (int c = 0; c < 4; ++c)
            #pragma unroll
            for (int reg = 0; reg < 4; ++reg) {
                float v = sc[c][reg];
                if (diag && (16 * c + r16 > 16 * w + quad * 4 + reg)) v = -INFINITY;
                float p = exp2f(v);
                Ps[w][quad * 4 + reg][16 * c + r16] = f2bf(p);
            }

        bf16x8 pf0 = *(const bf16x8*)&Ps[w][r16][quad * 8];
        bf16x8 pf1 = *(const bf16x8*)&Ps[w][r16][quad * 8 + 32];

        // ---- l += P . ones (on the MFMA pipe)
        accL = __builtin_amdgcn_mfma_f32_16x16x32_bf16(pf0, onesf, accL, 0, 0, 0);
        accL = __builtin_amdgcn_mfma_f32_16x16x32_bf16(pf1, onesf, accL, 0, 0, 0);

        // ---- O += P V
        #pragma unroll
        for (int c = 0; c < 4; ++c) {
            bf16x8 vf0 = *(const bf16x8*)&V_[16 * c + r16][(quad ^ rx) * 8];
            bf16x8 vf1 = *(const bf16x8*)&V_[16 * c + r16][((quad + 4) ^ rx) * 8];
            accO[c] = __builtin_amdgcn_mfma_f32_16x16x32_bf16(pf0, vf0, accO[c], 0, 0, 0);
            accO[c] = __builtin_amdgcn_mfma_f32_16x16x32_bf16(pf1, vf1, accO[c], 0, 0, 0);
        }
    }

    // ---- epilogue: l lives at lanes r16==0 (col 0 of accL) — broadcast per quad
    #pragma unroll
    for (int reg = 0; reg < 4; ++reg) {
        float l = __shfl(accL[reg], lane & 48);
        float invl = 1.0f / l;
        int row = q0 + 16 * w + quad * 4 + reg;
        ushort_t* op = O + (size_t)row * D + h * HD;
        #pragma unroll
        for (int c = 0; c < 4; ++c)
            op[16 * c + r16] = f2bf(accO[c][reg] * invl);
    }
}

// ---------------------------------------------------------------------------
// Workspace layout (exactly 32 MB, the footprint proven in R3):
//   [ 0M,  8M)  Xb   (x in bf16)        -> dead after QKV GEMM -> Ob
//   [ 8M, 20M)  WqkvT                   -> dead after QKV GEMM ->
//                   [ 8M, 16M) WoT   [16M, 18M) VTg
//   [20M, 32M)  QKVb
// ---------------------------------------------------------------------------
extern "C" void kernel_launch(void* const* d_in, const int* in_sizes, int n_in,
                              void* d_out, int out_size, void* d_ws, size_t ws_size,
                              hipStream_t stream) {
    const float* x    = (const float*)d_in[0];
    const float* cosT = (const float*)d_in[1];
    const float* sinT = (const float*)d_in[2];
    const float* g_q  = (const float*)d_in[3];
    const float* g_k  = (const float*)d_in[4];
    const float* Wq   = (const float*)d_in[5];
    const float* Wk   = (const float*)d_in[6];
    const float* Wv   = (const float*)d_in[7];
    const float* Wo   = (const float*)d_in[8];
    float* out = (float*)d_out;

    char* base = (char*)d_ws;
    ushort_t* Xb    = (ushort_t*)base;
    ushort_t* WqkvT = (ushort_t*)(base + 8388608);
    ushort_t* QKVb  = (ushort_t*)(base + 20971520);
    ushort_t* WoT   = (ushort_t*)(base + 8388608);    // alias into dead WqkvT
    ushort_t* VTg   = (ushort_t*)(base + 16777216);   // alias into dead WqkvT
    ushort_t* Ob    = Xb;                              // alias into dead Xb

    // 1. convert x to bf16
    convert_bf16<<<(S * D) / 1024, 256, 0, stream>>>(x, Xb, S * D);
    // 2. transpose-convert Wq|Wk|Wv into fused [3072, 2048] bf16
    transpose_w<<<dim3(2048 / 32, 2048 / 32), 256, 0, stream>>>(Wq, WqkvT, 2048, 2048, 2048, 0);
    transpose_w<<<dim3(512 / 32, 2048 / 32), 256, 0, stream>>>(Wk, WqkvT, 2048, 512, 2048, 2048);
    transpose_w<<<dim3(512 / 32, 2048 / 32), 256, 0, stream>>>(Wv, WqkvT, 2048, 512, 2048, 2560);
    // 3. fused QKV projection (bf16 out)
    gemm_bt<ushort_t><<<dim3(QKV_N / 128, S / 128), 256, 0, stream>>>(Xb, WqkvT, QKVb, S, QKV_N, D);
    // 4. RMSNorm + RoPE on Q,K parts
    rmsnorm_rope_b<<<dim3(S, 10), 256, 0, stream>>>(QKVb, g_q, g_k, cosT, sinT);
    // 5. V^T into the now-dead WqkvT space; Wo transpose likewise
    transpose_v<<<dim3(S / 32, 512 / 32), 256, 0, stream>>>(QKVb, VTg);
    transpose_w<<<dim3(2048 / 32, 2048 / 32), 256, 0, stream>>>(Wo, WoT, 2048, 2048, 2048, 0);
    // 6. MFMA flash attention v2
    flash_attn_mfma<<<dim3(S / 64, NQ), 256, 0, stream>>>(QKVb, VTg, Ob);
    // 7. output projection (fp32 out)
    gemm_bt<float><<<dim3(D / 128, S / 128), 256, 0, stream>>>(Ob, WoT, out, S, D, D);
}

// Round 6
// 282.061 us; speedup vs baseline: 24.6247x; 1.1010x over previous
//
#include <hip/hip_runtime.h>
#include <hip/hip_bf16.h>
#include <math.h>

#define S 2048
#define D 2048
#define NQ 32
#define NKV 8
#define HD 64
#define HALF 32
#define NREP 4
#define QKV_N 3072           // NQ*HD + 2*NKV*HD
#define KCOL 2048            // K starts here in fused QKV buffer
#define VCOL 2560            // V starts here

typedef unsigned short ushort_t;
typedef __attribute__((ext_vector_type(8))) short bf16x8;   // 8 bf16 = 4 VGPRs
typedef __attribute__((ext_vector_type(4))) float f32x4;
typedef float f4 __attribute__((ext_vector_type(4)));

__device__ __forceinline__ ushort_t f2bf(float f) {
    __hip_bfloat16 h = __float2bfloat16(f);
    return *reinterpret_cast<ushort_t*>(&h);
}
__device__ __forceinline__ float bf2f(ushort_t u) {
    __hip_bfloat16 h = *reinterpret_cast<__hip_bfloat16*>(&u);
    return __bfloat162float(h);
}

// async 16B global -> LDS (LDS base wave-uniform; HW scatters lane*16)
__device__ __forceinline__ void load_lds16(const ushort_t* g, ushort_t* l) {
    __builtin_amdgcn_global_load_lds(
        (const __attribute__((address_space(1))) unsigned int*)g,
        (__attribute__((address_space(3))) unsigned int*)l,
        16, 0, 0);
}

// ---------------------------------------------------------------------------
__global__ __launch_bounds__(256) void convert_bf16(const float* __restrict__ src,
                                                    ushort_t* __restrict__ dst, int n) {
    int i = (blockIdx.x * 256 + threadIdx.x) * 4;
    if (i + 3 < n) {
        f4 v = *(const f4*)&src[i];
        dst[i + 0] = f2bf(v[0]);
        dst[i + 1] = f2bf(v[1]);
        dst[i + 2] = f2bf(v[2]);
        dst[i + 3] = f2bf(v[3]);
    }
}

__global__ __launch_bounds__(256) void zero_f32(f4* __restrict__ p, int n4) {
    int i = blockIdx.x * 256 + threadIdx.x;
    if (i < n4) p[i] = (f4){0.f, 0.f, 0.f, 0.f};
}

// ---------------------------------------------------------------------------
// Transposing convert (fp32 -> bf16): dst[(row_off+n)*pitch + k] = src[k*N + n]
// ---------------------------------------------------------------------------
__global__ __launch_bounds__(256) void transpose_w(const float* __restrict__ src,
                                                   ushort_t* __restrict__ dst,
                                                   int Kdim, int N, int pitch, int row_off) {
    __shared__ float tile[32][33];
    const int n0 = blockIdx.x * 32, k0 = blockIdx.y * 32;
    const int tx = threadIdx.x & 31, ty = threadIdx.x >> 5;
    #pragma unroll
    for (int i = 0; i < 32; i += 8)
        tile[ty + i][tx] = src[(size_t)(k0 + ty + i) * N + (n0 + tx)];
    __syncthreads();
    #pragma unroll
    for (int i = 0; i < 32; i += 8)
        dst[(size_t)(row_off + n0 + ty + i) * pitch + (k0 + tx)] = f2bf(tile[tx][ty + i]);
}

// ---------------------------------------------------------------------------
// bf16 transpose of the V part of QKV: VTg[d][s] = QKV[s][VCOL + d]
// ---------------------------------------------------------------------------
__global__ __launch_bounds__(256) void transpose_v(const ushort_t* __restrict__ src,
                                                   ushort_t* __restrict__ dst) {
    __shared__ ushort_t tile[32][33];
    const int s0 = blockIdx.x * 32, d0 = blockIdx.y * 32;
    const int tx = threadIdx.x & 31, ty = threadIdx.x >> 5;
    #pragma unroll
    for (int i = 0; i < 32; i += 8)
        tile[ty + i][tx] = src[(size_t)(s0 + ty + i) * QKV_N + VCOL + d0 + tx];
    __syncthreads();
    #pragma unroll
    for (int i = 0; i < 32; i += 8)
        dst[(size_t)(d0 + ty + i) * S + s0 + tx] = tile[tx][ty + i];
}

// ---------------------------------------------------------------------------
// bf16 MFMA GEMM, 64x128 (MxN) tile, 4 waves at 32x64, BK=32, 12 KB LDS.
// Smaller tile than m97's 128x128 -> 2-3x more blocks -> >=3 blocks/CU at
// this problem's shapes (m114: wave-level overlap needs co-residency).
// ---------------------------------------------------------------------------
template <typename OutT>
__global__ __launch_bounds__(256) void gemm_bt64(const ushort_t* __restrict__ A,
                                                 const ushort_t* __restrict__ BT,
                                                 OutT* __restrict__ C,
                                                 int M, int N, int Kdim) {
    __shared__ ushort_t As[64][32];    // 4 KB
    __shared__ ushort_t Bs[128][32];   // 8 KB
    const int tid = threadIdx.x;
    const int w = tid >> 6, lane = tid & 63;
    const int r16 = lane & 15, quad = lane >> 4;
    const int wm = (w >> 1) * 32, wn = (w & 1) * 64;
    const int bm = blockIdx.y * 64, bn = blockIdx.x * 128;
    const int sr = lane >> 2;
    const int sc8 = (lane & 3) * 8;

    f32x4 acc[2][4];
    #pragma unroll
    for (int r = 0; r < 2; ++r)
        #pragma unroll
        for (int c = 0; c < 4; ++c) acc[r][c] = (f32x4){0.f, 0.f, 0.f, 0.f};

    for (int k0 = 0; k0 < Kdim; k0 += 32) {
        __syncthreads();
        // A: wave w stages rows [w*16, w*16+16)
        load_lds16(A + (size_t)(bm + w * 16 + sr) * Kdim + k0 + sc8, &As[w * 16][0]);
        // B: wave w stages rows [w*32, w*32+32)
        #pragma unroll
        for (int i = 0; i < 2; ++i)
            load_lds16(BT + (size_t)(bn + w * 32 + i * 16 + sr) * Kdim + k0 + sc8,
                       &Bs[w * 32 + i * 16][0]);
        __syncthreads();

        bf16x8 af[2], bfr[4];
        #pragma unroll
        for (int r = 0; r < 2; ++r) af[r]  = *(const bf16x8*)&As[wm + 16 * r + r16][quad * 8];
        #pragma unroll
        for (int c = 0; c < 4; ++c) bfr[c] = *(const bf16x8*)&Bs[wn + 16 * c + r16][quad * 8];
        #pragma unroll
        for (int r = 0; r < 2; ++r)
            #pragma unroll
            for (int c = 0; c < 4; ++c)
                acc[r][c] = __builtin_amdgcn_mfma_f32_16x16x32_bf16(af[r], bfr[c], acc[r][c], 0, 0, 0);
    }

    #pragma unroll
    for (int r = 0; r < 2; ++r)
        #pragma unroll
        for (int c = 0; c < 4; ++c)
            #pragma unroll
            for (int reg = 0; reg < 4; ++reg) {
                int row = bm + wm + 16 * r + quad * 4 + reg;
                int col = bn + wn + 16 * c + r16;
                float v = acc[r][c][reg];
                if constexpr (sizeof(OutT) == 2) C[(size_t)row * N + col] = (OutT)f2bf(v);
                else                             C[(size_t)row * N + col] = (OutT)v;
            }
}

// ---------------------------------------------------------------------------
// RMSNorm + RoPE on the fused QKV bf16 buffer (Q and K parts only), in place.
// ---------------------------------------------------------------------------
__global__ __launch_bounds__(256) void rmsnorm_rope_b(ushort_t* __restrict__ QKV,
                                                      const float* __restrict__ gq,
                                                      const float* __restrict__ gk,
                                                      const float* __restrict__ cosT,
                                                      const float* __restrict__ sinT) {
    const int s = blockIdx.x;
    const int w = threadIdx.x >> 6;
    const int hh = blockIdx.y * 4 + w;
    const int d = threadIdx.x & 63;
    const float* g;
    int col;
    if (hh < NQ) { g = gq; col = hh * HD; }
    else         { g = gk; col = KCOL + (hh - NQ) * HD; }

    ushort_t* xp = QKV + (size_t)s * QKV_N + col;
    float v = bf2f(xp[d]);
    float ss = v * v;
    #pragma unroll
    for (int off = 32; off > 0; off >>= 1) ss += __shfl_down(ss, off);
    ss = __shfl(ss, 0);
    float inv = rsqrtf(ss * (1.0f / HD) + 1e-6f);
    float xn = v * inv * g[d];

    float other = __shfl(xn, d ^ 32);
    float c = cosT[(size_t)s * HALF + (d & 31)];
    float sn = sinT[(size_t)s * HALF + (d & 31)];
    float outv = (d < HALF) ? (xn * c - other * sn) : (other * sn + xn * c);
    xp[d] = f2bf(outv);
}

// ---------------------------------------------------------------------------
// MFMA flash attention v3: split-K causal GQA. grid (48, NQ), block 256.
// blockIdx.x -> (qt, key-chunk):
//   bx <  16: qt = 16+bx,  tiles [0,16)      -> atomic partial
//   bx >= 16: qt = 47-bx;  qt>=16: tiles [16,qt+1) -> atomic partial
//                          qt< 16: tiles [0,qt+1)  -> direct write
// Static-max softmax => partials combine by pure addition (atomicAdd fp32).
// ---------------------------------------------------------------------------
__global__ __launch_bounds__(256) void flash_attn_mfma(const ushort_t* __restrict__ QKV,
                                                       const ushort_t* __restrict__ VTg,
                                                       ushort_t* __restrict__ O,
                                                       float* __restrict__ AccBuf,
                                                       float* __restrict__ AccL) {
    __shared__ ushort_t Ks[2][64][64];   // [buf][key][hd], 16B chunks XOR-swizzled
    __shared__ ushort_t Vt[2][64][64];   // [buf][hd][key]
    __shared__ ushort_t Ps[4][16][72];   // per-wave [row][key]

    const int bx = blockIdx.x;
    int qt, tb, te;
    bool atom;
    if (bx < 16) { qt = 16 + bx; tb = 0; te = 16; atom = true; }
    else         { qt = 47 - bx; atom = (qt >= 16); tb = atom ? 16 : 0; te = qt + 1; }

    const int q0 = qt * 64;
    const int h  = blockIdx.y;
    const int kvh = h >> 2;
    const int tid = threadIdx.x;
    const int w = tid >> 6, lane = tid & 63;
    const int r16 = lane & 15, quad = lane >> 4;
    const int kcol = KCOL + kvh * HD;
    const int vtrow0 = kvh * HD;
    const int rsub = lane >> 3;
    const int jlog = (lane & 7) ^ rsub;
    const int rx = r16 & 7;

    // Q fragments (A-layout), prescaled by 1/sqrt(HD) * log2(e)
    const ushort_t* qrow = QKV + (size_t)(q0 + 16 * w + r16) * QKV_N + h * HD;
    bf16x8 qf0, qf1;
    {
        bf16x8 r0 = *(const bf16x8*)(qrow + quad * 8);
        bf16x8 r1 = *(const bf16x8*)(qrow + quad * 8 + 32);
        #pragma unroll
        for (int j = 0; j < 8; ++j) {
            qf0[j] = (short)f2bf(bf2f((ushort_t)r0[j]) * 0.18033688f);
            qf1[j] = (short)f2bf(bf2f((ushort_t)r1[j]) * 0.18033688f);
        }
    }

    // ones B-fragment for row-sum MFMA: B[k][n] = (n==0)
    bf16x8 onesf;
    {
        ushort_t ov = (r16 == 0) ? (ushort_t)0x3F80 : (ushort_t)0;
        #pragma unroll
        for (int j = 0; j < 8; ++j) onesf[j] = (short)ov;
    }

    f32x4 accO[4];
    f32x4 accL = (f32x4){0.f, 0.f, 0.f, 0.f};
    #pragma unroll
    for (int c = 0; c < 4; ++c) accO[c] = (f32x4){0.f, 0.f, 0.f, 0.f};

    auto stage = [&](int b, int t0) {
        #pragma unroll
        for (int i = 0; i < 2; ++i) {
            int base = w * 16 + i * 8;
            int row = base + rsub;
            load_lds16(QKV + (size_t)(t0 + row) * QKV_N + kcol + jlog * 8, &Ks[b][base][0]);
            load_lds16(VTg + (size_t)(vtrow0 + row) * S + t0 + jlog * 8, &Vt[b][base][0]);
        }
    };

    stage(tb & 1, tb * 64);

    for (int t = tb; t < te; ++t) {
        __syncthreads();
        if (t + 1 < te) stage((t + 1) & 1, (t + 1) * 64);

        const ushort_t (*K_)[64] = Ks[t & 1];
        const ushort_t (*V_)[64] = Vt[t & 1];
        const bool diag = (t == qt);

        // ---- S = Qs K^T
        f32x4 sc[4];
        #pragma unroll
        for (int c = 0; c < 4; ++c) {
            bf16x8 kf0 = *(const bf16x8*)&K_[16 * c + r16][(quad ^ rx) * 8];
            bf16x8 kf1 = *(const bf16x8*)&K_[16 * c + r16][((quad + 4) ^ rx) * 8];
            f32x4 z = (f32x4){0.f, 0.f, 0.f, 0.f};
            z = __builtin_amdgcn_mfma_f32_16x16x32_bf16(qf0, kf0, z, 0, 0, 0);
            z = __builtin_amdgcn_mfma_f32_16x16x32_bf16(qf1, kf1, z, 0, 0, 0);
            sc[c] = z;
        }

        // ---- p = exp2(s), causal mask on diagonal tile, store to Ps (C->A layout)
        #pragma unroll
        for (int c = 0; c < 4; ++c)
            #pragma unroll
            for (int reg = 0; reg < 4; ++reg) {
                float v = sc[c][reg];
                if (diag && (16 * c + r16 > 16 * w + quad * 4 + reg)) v = -INFINITY;
                float p = exp2f(v);
                Ps[w][quad * 4 + reg][16 * c + r16] = f2bf(p);
            }

        bf16x8 pf0 = *(const bf16x8*)&Ps[w][r16][quad * 8];
        bf16x8 pf1 = *(const bf16x8*)&Ps[w][r16][quad * 8 + 32];

        // ---- l += P . ones (on the MFMA pipe)
        accL = __builtin_amdgcn_mfma_f32_16x16x32_bf16(pf0, onesf, accL, 0, 0, 0);
        accL = __builtin_amdgcn_mfma_f32_16x16x32_bf16(pf1, onesf, accL, 0, 0, 0);

        // ---- O += P V
        #pragma unroll
        for (int c = 0; c < 4; ++c) {
            bf16x8 vf0 = *(const bf16x8*)&V_[16 * c + r16][(quad ^ rx) * 8];
            bf16x8 vf1 = *(const bf16x8*)&V_[16 * c + r16][((quad + 4) ^ rx) * 8];
            accO[c] = __builtin_amdgcn_mfma_f32_16x16x32_bf16(pf0, vf0, accO[c], 0, 0, 0);
            accO[c] = __builtin_amdgcn_mfma_f32_16x16x32_bf16(pf1, vf1, accO[c], 0, 0, 0);
        }
    }

    if (!atom) {
        // direct epilogue: l at lanes r16==0 — broadcast within quad
        #pragma unroll
        for (int reg = 0; reg < 4; ++reg) {
            float l = __shfl(accL[reg], lane & 48);
            float invl = 1.0f / l;
            int row = q0 + 16 * w + quad * 4 + reg;
            ushort_t* op = O + (size_t)row * D + h * HD;
            #pragma unroll
            for (int c = 0; c < 4; ++c)
                op[16 * c + r16] = f2bf(accO[c][reg] * invl);
        }
    } else {
        const int pair = (qt - 16) * 32 + h;
        float* ab = AccBuf + (size_t)pair * 4096;
        #pragma unroll
        for (int reg = 0; reg < 4; ++reg) {
            int row = 16 * w + quad * 4 + reg;
            #pragma unroll
            for (int c = 0; c < 4; ++c)
                atomicAdd(&ab[row * 64 + 16 * c + r16], accO[c][reg]);
        }
        if (r16 == 0) {
            #pragma unroll
            for (int reg = 0; reg < 4; ++reg)
                atomicAdd(&AccL[pair * 64 + 16 * w + quad * 4 + reg], accL[reg]);
        }
    }
}

// ---------------------------------------------------------------------------
// Combine split-K partials: O = AccBuf / AccL for qt in [16,32).
// ---------------------------------------------------------------------------
__global__ __launch_bounds__(256) void normalize_o(const float* __restrict__ AccBuf,
                                                   const float* __restrict__ AccL,
                                                   ushort_t* __restrict__ O) {
    const int pair = blockIdx.x;             // 512
    const int qt = 16 + (pair >> 5);
    const int h  = pair & 31;
    const float* ab = AccBuf + (size_t)pair * 4096;
    const float* lp = AccL + pair * 64;
    for (int i = threadIdx.x; i < 4096; i += 256) {
        int row = i >> 6, d = i & 63;
        O[(size_t)(qt * 64 + row) * D + h * HD + d] = f2bf(ab[i] / lp[row]);
    }
}

// ---------------------------------------------------------------------------
// Workspace (32 MB, footprint proven in R3):
//   [ 0M,  8M)  Xb (x bf16)          -> dead after QKV GEMM -> Ob
//   [ 8M, 20M)  WqkvT                -> dead after QKV GEMM ->
//                  [8M,16M) AccBuf (then WoT after normalize)
//                  [16M,18M) VTg    [18M,18.125M) AccL
//   [20M, 32M)  QKVb
// ---------------------------------------------------------------------------
extern "C" void kernel_launch(void* const* d_in, const int* in_sizes, int n_in,
                              void* d_out, int out_size, void* d_ws, size_t ws_size,
                              hipStream_t stream) {
    const float* x    = (const float*)d_in[0];
    const float* cosT = (const float*)d_in[1];
    const float* sinT = (const float*)d_in[2];
    const float* g_q  = (const float*)d_in[3];
    const float* g_k  = (const float*)d_in[4];
    const float* Wq   = (const float*)d_in[5];
    const float* Wk   = (const float*)d_in[6];
    const float* Wv   = (const float*)d_in[7];
    const float* Wo   = (const float*)d_in[8];
    float* out = (float*)d_out;

    char* base = (char*)d_ws;
    ushort_t* Xb     = (ushort_t*)base;
    ushort_t* WqkvT  = (ushort_t*)(base + 8388608);
    ushort_t* QKVb   = (ushort_t*)(base + 20971520);
    float*    AccBuf = (float*)(base + 8388608);      // alias dead WqkvT [8M,16M)
    ushort_t* WoT    = (ushort_t*)(base + 8388608);   // alias, after normalize
    ushort_t* VTg    = (ushort_t*)(base + 16777216);  // [16M,18M)
    float*    AccL   = (float*)(base + 18874368);     // [18M, +128KB)
    ushort_t* Ob     = Xb;

    // 1. convert x to bf16
    convert_bf16<<<(S * D) / 1024, 256, 0, stream>>>(x, Xb, S * D);
    // 2. transpose-convert Wq|Wk|Wv into fused [3072, 2048] bf16
    transpose_w<<<dim3(2048 / 32, 2048 / 32), 256, 0, stream>>>(Wq, WqkvT, 2048, 2048, 2048, 0);
    transpose_w<<<dim3(512 / 32, 2048 / 32), 256, 0, stream>>>(Wk, WqkvT, 2048, 512, 2048, 2048);
    transpose_w<<<dim3(512 / 32, 2048 / 32), 256, 0, stream>>>(Wv, WqkvT, 2048, 512, 2048, 2560);
    // 3. fused QKV projection (bf16 out)
    gemm_bt64<ushort_t><<<dim3(QKV_N / 128, S / 64), 256, 0, stream>>>(Xb, WqkvT, QKVb, S, QKV_N, D);
    // 4. RMSNorm + RoPE on Q,K parts
    rmsnorm_rope_b<<<dim3(S, 10), 256, 0, stream>>>(QKVb, g_q, g_k, cosT, sinT);
    // 5. V^T + zero the split-K accumulators (WqkvT now dead)
    transpose_v<<<dim3(S / 32, 512 / 32), 256, 0, stream>>>(QKVb, VTg);
    zero_f32<<<(2097152 / 4 + 255) / 256, 256, 0, stream>>>((f4*)AccBuf, 2097152 / 4);
    zero_f32<<<(32768 / 4 + 255) / 256, 256, 0, stream>>>((f4*)AccL, 32768 / 4);
    // 6. split-K MFMA flash attention
    flash_attn_mfma<<<dim3(48, NQ), 256, 0, stream>>>(QKVb, VTg, Ob, AccBuf, AccL);
    // 7. combine partials for qt >= 16
    normalize_o<<<512, 256, 0, stream>>>(AccBuf, AccL, Ob);
    // 8. Wo transpose into the now-dead AccBuf space, then output projection
    transpose_w<<<dim3(2048 / 32, 2048 / 32), 256, 0, stream>>>(Wo, WoT, 2048, 2048, 2048, 0);
    gemm_bt64<float><<<dim3(D / 128, S / 64), 256, 0, stream>>>(Ob, WoT, out, S, D, D);
}

// Round 7
// 257.451 us; speedup vs baseline: 26.9786x; 1.0956x over previous
//
#include <hip/hip_runtime.h>
#include <hip/hip_bf16.h>
#include <math.h>

#define S 2048
#define D 2048
#define NQ 32
#define NKV 8
#define HD 64
#define HALF 32
#define NREP 4
#define QKV_N 3072           // NQ*HD + 2*NKV*HD
#define KCOL 2048            // K starts here in fused QKV buffer
#define VCOL 2560            // V starts here

typedef unsigned short ushort_t;
typedef __attribute__((ext_vector_type(8))) short bf16x8;   // 8 bf16 = 4 VGPRs
typedef __attribute__((ext_vector_type(4))) float f32x4;
typedef float f4 __attribute__((ext_vector_type(4)));

__device__ __forceinline__ ushort_t f2bf(float f) {
    __hip_bfloat16 h = __float2bfloat16(f);
    return *reinterpret_cast<ushort_t*>(&h);
}
__device__ __forceinline__ float bf2f(ushort_t u) {
    __hip_bfloat16 h = *reinterpret_cast<__hip_bfloat16*>(&u);
    return __bfloat162float(h);
}

// async 16B global -> LDS (LDS base wave-uniform; HW scatters lane*16)
__device__ __forceinline__ void load_lds16(const ushort_t* g, ushort_t* l) {
    __builtin_amdgcn_global_load_lds(
        (const __attribute__((address_space(1))) unsigned int*)g,
        (__attribute__((address_space(3))) unsigned int*)l,
        16, 0, 0);
}

// ---------------------------------------------------------------------------
// prep_all: x fp32->bf16 convert (blocks [0,4096)) + Wq/Wk/Wv transposing
// converts into fused WqkvT [3072,2048] (blocks [4096,10240)).
// ---------------------------------------------------------------------------
__global__ __launch_bounds__(256) void prep_all(const float* __restrict__ x,
                                                ushort_t* __restrict__ Xb,
                                                const float* __restrict__ Wq,
                                                const float* __restrict__ Wk,
                                                const float* __restrict__ Wv,
                                                ushort_t* __restrict__ WqkvT) {
    __shared__ float tile[32][33];
    const int b = blockIdx.x;
    if (b < 4096) {
        int i = (b * 256 + threadIdx.x) * 4;
        f4 v = *(const f4*)&x[i];
        Xb[i + 0] = f2bf(v[0]);
        Xb[i + 1] = f2bf(v[1]);
        Xb[i + 2] = f2bf(v[2]);
        Xb[i + 3] = f2bf(v[3]);
        return;
    }
    const float* src; int N, row_off, t;
    if (b < 8192)      { src = Wq; N = 2048; row_off = 0;    t = b - 4096; }
    else if (b < 9216) { src = Wk; N = 512;  row_off = 2048; t = b - 8192; }
    else               { src = Wv; N = 512;  row_off = 2560; t = b - 9216; }
    const int ntn = N / 32;
    const int n0 = (t % ntn) * 32, k0 = (t / ntn) * 32;
    const int tx = threadIdx.x & 31, ty = threadIdx.x >> 5;
    #pragma unroll
    for (int i = 0; i < 32; i += 8)
        tile[ty + i][tx] = src[(size_t)(k0 + ty + i) * N + (n0 + tx)];
    __syncthreads();
    #pragma unroll
    for (int i = 0; i < 32; i += 8)
        WqkvT[(size_t)(row_off + n0 + ty + i) * 2048 + (k0 + tx)] = f2bf(tile[tx][ty + i]);
}

// ---------------------------------------------------------------------------
// bf16 MFMA GEMM, 64x64 tile, BK=64, 4 waves at 32x32, 16 KB LDS.
// Grid residency: QKV 1536 blocks = 6/CU; out-proj 1024 = 4/CU.
// ---------------------------------------------------------------------------
template <typename OutT>
__global__ __launch_bounds__(256) void gemm64(const ushort_t* __restrict__ A,
                                              const ushort_t* __restrict__ BT,
                                              OutT* __restrict__ C,
                                              int M, int N, int Kdim) {
    __shared__ ushort_t As[64][64];   // [row][k], 128B rows, 16B chunks XOR-swizzled
    __shared__ ushort_t Bs[64][64];
    const int tid = threadIdx.x;
    const int w = tid >> 6, lane = tid & 63;
    const int r16 = lane & 15, quad = lane >> 4;
    const int wm = (w >> 1) * 32, wn = (w & 1) * 32;
    const int bm = blockIdx.y * 64, bn = blockIdx.x * 64;
    const int srow = lane >> 3;                 // 0..7
    const int jl = (lane & 7) ^ srow;           // XOR-swizzled 16B chunk
    const int rx = r16 & 7;                     // read-side swizzle key

    f32x4 acc[2][2];
    #pragma unroll
    for (int r = 0; r < 2; ++r)
        #pragma unroll
        for (int c = 0; c < 2; ++c) acc[r][c] = (f32x4){0.f, 0.f, 0.f, 0.f};

    for (int k0 = 0; k0 < Kdim; k0 += 64) {
        __syncthreads();
        #pragma unroll
        for (int i = 0; i < 2; ++i) {
            int rbase = w * 16 + i * 8;
            load_lds16(A  + (size_t)(bm + rbase + srow) * Kdim + k0 + jl * 8, &As[rbase][0]);
            load_lds16(BT + (size_t)(bn + rbase + srow) * Kdim + k0 + jl * 8, &Bs[rbase][0]);
        }
        __syncthreads();

        #pragma unroll
        for (int h = 0; h < 2; ++h) {
            bf16x8 af[2], bfr[2];
            #pragma unroll
            for (int r = 0; r < 2; ++r)
                af[r]  = *(const bf16x8*)&As[wm + 16 * r + r16][((quad + 4 * h) ^ rx) * 8];
            #pragma unroll
            for (int c = 0; c < 2; ++c)
                bfr[c] = *(const bf16x8*)&Bs[wn + 16 * c + r16][((quad + 4 * h) ^ rx) * 8];
            #pragma unroll
            for (int r = 0; r < 2; ++r)
                #pragma unroll
                for (int c = 0; c < 2; ++c)
                    acc[r][c] = __builtin_amdgcn_mfma_f32_16x16x32_bf16(af[r], bfr[c], acc[r][c], 0, 0, 0);
        }
    }

    #pragma unroll
    for (int r = 0; r < 2; ++r)
        #pragma unroll
        for (int c = 0; c < 2; ++c)
            #pragma unroll
            for (int reg = 0; reg < 4; ++reg) {
                int row = bm + wm + 16 * r + quad * 4 + reg;
                int col = bn + wn + 16 * c + r16;
                float v = acc[r][c][reg];
                if constexpr (sizeof(OutT) == 2) C[(size_t)row * N + col] = (OutT)f2bf(v);
                else                             C[(size_t)row * N + col] = (OutT)v;
            }
}

// ---------------------------------------------------------------------------
// Fused: RMSNorm+RoPE (y<10), V transpose (y==10,x<1024), Wo transpose
// (remaining blocks). grid (2048, 13).
// ---------------------------------------------------------------------------
__global__ __launch_bounds__(256) void rms_rope_vwo(ushort_t* __restrict__ QKV,
                                                    const float* __restrict__ gq,
                                                    const float* __restrict__ gk,
                                                    const float* __restrict__ cosT,
                                                    const float* __restrict__ sinT,
                                                    ushort_t* __restrict__ VTg,
                                                    const float* __restrict__ Wo,
                                                    ushort_t* __restrict__ WoT) {
    const int y = blockIdx.y, xb = blockIdx.x;
    if (y < 10) {
        const int s = xb;
        const int w = threadIdx.x >> 6;
        const int hh = y * 4 + w;
        const int d = threadIdx.x & 63;
        const float* g;
        int col;
        if (hh < NQ) { g = gq; col = hh * HD; }
        else         { g = gk; col = KCOL + (hh - NQ) * HD; }
        ushort_t* xp = QKV + (size_t)s * QKV_N + col;
        float v = bf2f(xp[d]);
        float ss = v * v;
        #pragma unroll
        for (int off = 32; off > 0; off >>= 1) ss += __shfl_down(ss, off);
        ss = __shfl(ss, 0);
        float inv = rsqrtf(ss * (1.0f / HD) + 1e-6f);
        float xn = v * inv * g[d];
        float other = __shfl(xn, d ^ 32);
        float c = cosT[(size_t)s * HALF + (d & 31)];
        float sn = sinT[(size_t)s * HALF + (d & 31)];
        float outv = (d < HALF) ? (xn * c - other * sn) : (other * sn + xn * c);
        xp[d] = f2bf(outv);
        return;
    }
    const int tx = threadIdx.x & 31, ty = threadIdx.x >> 5;
    if (y == 10 && xb < 1024) {
        __shared__ ushort_t vt[32][33];
        const int s0 = (xb & 63) * 32, d0 = (xb >> 6) * 32;
        #pragma unroll
        for (int i = 0; i < 32; i += 8)
            vt[ty + i][tx] = QKV[(size_t)(s0 + ty + i) * QKV_N + VCOL + d0 + tx];
        __syncthreads();
        #pragma unroll
        for (int i = 0; i < 32; i += 8)
            VTg[(size_t)(d0 + ty + i) * S + s0 + tx] = vt[tx][ty + i];
        return;
    }
    int idx;
    if (y == 10)      idx = xb - 1024;           // [0,1024)
    else if (y == 11) idx = 1024 + xb;           // [1024,3072)
    else              idx = 3072 + xb;           // [3072,4096) for xb<1024
    if (idx < 0 || idx >= 4096) return;
    __shared__ float wt[32][33];
    const int n0 = (idx & 63) * 32, k0 = (idx >> 6) * 32;
    #pragma unroll
    for (int i = 0; i < 32; i += 8)
        wt[ty + i][tx] = Wo[(size_t)(k0 + ty + i) * 2048 + (n0 + tx)];
    __syncthreads();
    #pragma unroll
    for (int i = 0; i < 32; i += 8)
        WoT[(size_t)(n0 + ty + i) * 2048 + (k0 + tx)] = f2bf(wt[tx][ty + i]);
}

// ---------------------------------------------------------------------------
// zero AccBuf (in d_out, 8 MB) + AccL (128 KB)
// ---------------------------------------------------------------------------
__global__ __launch_bounds__(256) void zero_acc(f4* __restrict__ AccBuf4,
                                                f4* __restrict__ AccL4) {
    int i = blockIdx.x * 256 + threadIdx.x;
    if (i < 524288) AccBuf4[i] = (f4){0.f, 0.f, 0.f, 0.f};
    else if (i < 532480) AccL4[i - 524288] = (f4){0.f, 0.f, 0.f, 0.f};
}

// ---------------------------------------------------------------------------
// MFMA flash attention v4: split-K causal GQA, 32-key tiles, 21.5 KB LDS
// (~7 blocks/CU). grid (48, NQ), block 256 = 4 waves.
//   bx <  16: qt = 16+bx,  tiles [0,32)           -> atomic partial
//   bx >= 16: qt = 47-bx;  qt>=16: [32, 2qt+2)    -> atomic partial
//                          qt< 16: [0, 2qt+2)     -> direct write
// Static-max softmax => partials combine by pure addition.
// ---------------------------------------------------------------------------
__global__ __launch_bounds__(256) void flash_attn_mfma(const ushort_t* __restrict__ QKV,
                                                       const ushort_t* __restrict__ VTg,
                                                       ushort_t* __restrict__ O,
                                                       float* __restrict__ AccBuf,
                                                       float* __restrict__ AccL) {
    __shared__ ushort_t Ks[2][32][64];   // [buf][key][hd]
    __shared__ ushort_t Vt[2][64][32];   // [buf][hd][key]
    __shared__ ushort_t Ps[4][16][40];   // per-wave [row][key]

    const int bx = blockIdx.x;
    int qt, tb, te;
    bool atom;
    if (bx < 16) { qt = 16 + bx; tb = 0; te = 32; atom = true; }
    else         { qt = 47 - bx; atom = (qt >= 16); tb = atom ? 32 : 0; te = 2 * qt + 2; }

    const int q0 = qt * 64;
    const int h  = blockIdx.y;
    const int kvh = h >> 2;
    const int tid = threadIdx.x;
    const int w = tid >> 6, lane = tid & 63;
    const int r16 = lane & 15, quad = lane >> 4;
    const int kcol = KCOL + kvh * HD;
    const int vtrow0 = kvh * HD;
    const int krow = lane >> 3;                 // K staging: row within 8-chunk
    const int jl = (lane & 7) ^ krow;           // K staging chunk (XOR)
    const int vrow = lane >> 2;                 // V staging: row within 16-chunk
    const int jv = (lane & 3) ^ (vrow & 3);     // V staging chunk (XOR)
    const int rx = r16 & 7;
    const int rx3 = r16 & 3;

    // Q fragments (A-layout), prescaled by 1/sqrt(HD) * log2(e)
    const ushort_t* qrow = QKV + (size_t)(q0 + 16 * w + r16) * QKV_N + h * HD;
    bf16x8 qf0, qf1;
    {
        bf16x8 r0 = *(const bf16x8*)(qrow + quad * 8);
        bf16x8 r1 = *(const bf16x8*)(qrow + quad * 8 + 32);
        #pragma unroll
        for (int j = 0; j < 8; ++j) {
            qf0[j] = (short)f2bf(bf2f((ushort_t)r0[j]) * 0.18033688f);
            qf1[j] = (short)f2bf(bf2f((ushort_t)r1[j]) * 0.18033688f);
        }
    }

    // ones B-fragment for row-sum MFMA: B[k][n] = (n==0)
    bf16x8 onesf;
    {
        ushort_t ov = (r16 == 0) ? (ushort_t)0x3F80 : (ushort_t)0;
        #pragma unroll
        for (int j = 0; j < 8; ++j) onesf[j] = (short)ov;
    }

    f32x4 accO[4];
    f32x4 accL = (f32x4){0.f, 0.f, 0.f, 0.f};
    #pragma unroll
    for (int c = 0; c < 4; ++c) accO[c] = (f32x4){0.f, 0.f, 0.f, 0.f};

    auto stage = [&](int b, int t) {
        const int kb = t * 32;
        load_lds16(QKV + (size_t)(kb + w * 8 + krow) * QKV_N + kcol + jl * 8,
                   &Ks[b][w * 8][0]);
        load_lds16(VTg + (size_t)(vtrow0 + w * 16 + vrow) * S + kb + jv * 8,
                   &Vt[b][w * 16][0]);
    };

    stage(tb & 1, tb);

    for (int t = tb; t < te; ++t) {
        __syncthreads();
        if (t + 1 < te) stage((t + 1) & 1, t + 1);

        const ushort_t (*K_)[64] = Ks[t & 1];
        const ushort_t (*V_)[32] = Vt[t & 1];
        const int rel = t * 32 - q0;
        const bool maskt = (rel >= 0);

        // ---- S = Qs K^T (2 col-chunks of 16 keys)
        f32x4 sc[2];
        #pragma unroll
        for (int c = 0; c < 2; ++c) {
            bf16x8 kf0 = *(const bf16x8*)&K_[16 * c + r16][(quad ^ rx) * 8];
            bf16x8 kf1 = *(const bf16x8*)&K_[16 * c + r16][((quad + 4) ^ rx) * 8];
            f32x4 z = (f32x4){0.f, 0.f, 0.f, 0.f};
            z = __builtin_amdgcn_mfma_f32_16x16x32_bf16(qf0, kf0, z, 0, 0, 0);
            z = __builtin_amdgcn_mfma_f32_16x16x32_bf16(qf1, kf1, z, 0, 0, 0);
            sc[c] = z;
        }

        // ---- p = exp2(s), causal mask, store to Ps (C->A layout)
        #pragma unroll
        for (int c = 0; c < 2; ++c)
            #pragma unroll
            for (int reg = 0; reg < 4; ++reg) {
                float v = sc[c][reg];
                if (maskt && (rel + 16 * c + r16 > 16 * w + quad * 4 + reg)) v = -INFINITY;
                Ps[w][quad * 4 + reg][16 * c + r16] = f2bf(exp2f(v));
            }

        bf16x8 pf = *(const bf16x8*)&Ps[w][r16][quad * 8];

        // ---- l += P . ones ; O += P V  (all on the MFMA pipe)
        accL = __builtin_amdgcn_mfma_f32_16x16x32_bf16(pf, onesf, accL, 0, 0, 0);
        #pragma unroll
        for (int c = 0; c < 4; ++c) {
            bf16x8 vf = *(const bf16x8*)&V_[16 * c + r16][(quad ^ rx3) * 8];
            accO[c] = __builtin_amdgcn_mfma_f32_16x16x32_bf16(pf, vf, accO[c], 0, 0, 0);
        }
    }

    if (!atom) {
        #pragma unroll
        for (int reg = 0; reg < 4; ++reg) {
            float l = __shfl(accL[reg], lane & 48);
            float invl = 1.0f / l;
            int row = q0 + 16 * w + quad * 4 + reg;
            ushort_t* op = O + (size_t)row * D + h * HD;
            #pragma unroll
            for (int c = 0; c < 4; ++c)
                op[16 * c + r16] = f2bf(accO[c][reg] * invl);
        }
    } else {
        const int pair = (qt - 16) * 32 + h;
        float* ab = AccBuf + (size_t)pair * 4096;
        #pragma unroll
        for (int reg = 0; reg < 4; ++reg) {
            int row = 16 * w + quad * 4 + reg;
            #pragma unroll
            for (int c = 0; c < 4; ++c)
                atomicAdd(&ab[row * 64 + 16 * c + r16], accO[c][reg]);
        }
        if (r16 == 0) {
            #pragma unroll
            for (int reg = 0; reg < 4; ++reg)
                atomicAdd(&AccL[pair * 64 + 16 * w + quad * 4 + reg], accL[reg]);
        }
    }
}

// ---------------------------------------------------------------------------
// Combine split-K partials: O = AccBuf / AccL for qt in [16,32).
// ---------------------------------------------------------------------------
__global__ __launch_bounds__(256) void normalize_o(const float* __restrict__ AccBuf,
                                                   const float* __restrict__ AccL,
                                                   ushort_t* __restrict__ O) {
    const int pair = blockIdx.x;
    const int qt = 16 + (pair >> 5);
    const int h  = pair & 31;
    const float* ab = AccBuf + (size_t)pair * 4096;
    const float* lp = AccL + pair * 64;
    for (int i = threadIdx.x; i < 4096; i += 256) {
        int row = i >> 6, d = i & 63;
        O[(size_t)(qt * 64 + row) * D + h * HD + d] = f2bf(ab[i] / lp[row]);
    }
}

// ---------------------------------------------------------------------------
// Workspace (32 MB) + d_out (16 MB fp32) as scratch:
//   ws[ 0M, 8M)  Xb (x bf16)            -> dead after QKV GEMM -> Ob
//   ws[ 8M,20M)  WqkvT                  -> dead after QKV GEMM ->
//                   [8M,16M) WoT   [16M,18M) VTg   [18M,18.125M) AccL
//   ws[20M,32M)  QKVb
//   d_out[0,8M)  AccBuf (fp32 split-K partials), overwritten by out-proj
// ---------------------------------------------------------------------------
extern "C" void kernel_launch(void* const* d_in, const int* in_sizes, int n_in,
                              void* d_out, int out_size, void* d_ws, size_t ws_size,
                              hipStream_t stream) {
    const float* x    = (const float*)d_in[0];
    const float* cosT = (const float*)d_in[1];
    const float* sinT = (const float*)d_in[2];
    const float* g_q  = (const float*)d_in[3];
    const float* g_k  = (const float*)d_in[4];
    const float* Wq   = (const float*)d_in[5];
    const float* Wk   = (const float*)d_in[6];
    const float* Wv   = (const float*)d_in[7];
    const float* Wo   = (const float*)d_in[8];
    float* out = (float*)d_out;

    char* base = (char*)d_ws;
    ushort_t* Xb    = (ushort_t*)base;
    ushort_t* WqkvT = (ushort_t*)(base + 8388608);
    ushort_t* QKVb  = (ushort_t*)(base + 20971520);
    ushort_t* WoT   = (ushort_t*)(base + 8388608);    // alias dead WqkvT
    ushort_t* VTg   = (ushort_t*)(base + 16777216);   // alias dead WqkvT
    float*    AccL  = (float*)(base + 18874368);      // alias dead WqkvT
    float*    AccBuf = (float*)d_out;                  // d_out[0,8M) as scratch
    ushort_t* Ob    = Xb;                              // alias dead Xb

    // 1. x convert + Wq/Wk/Wv transpose-convert
    prep_all<<<10240, 256, 0, stream>>>(x, Xb, Wq, Wk, Wv, WqkvT);
    // 2. fused QKV projection (bf16 out), 1536 blocks = 6/CU
    gemm64<ushort_t><<<dim3(QKV_N / 64, S / 64), 256, 0, stream>>>(Xb, WqkvT, QKVb, S, QKV_N, D);
    // 3. RMSNorm+RoPE on Q,K + V^T + Wo transpose (WqkvT now dead)
    rms_rope_vwo<<<dim3(2048, 13), 256, 0, stream>>>(QKVb, g_q, g_k, cosT, sinT, VTg, Wo, WoT);
    // 4. zero split-K accumulators
    zero_acc<<<2080, 256, 0, stream>>>((f4*)AccBuf, (f4*)AccL);
    // 5. split-K MFMA flash attention (32-key tiles)
    flash_attn_mfma<<<dim3(48, NQ), 256, 0, stream>>>(QKVb, VTg, Ob, AccBuf, AccL);
    // 6. combine partials for qt >= 16
    normalize_o<<<512, 256, 0, stream>>>(AccBuf, AccL, Ob);
    // 7. output projection (fp32 out, overwrites AccBuf region of d_out)
    gemm64<float><<<dim3(D / 64, S / 64), 256, 0, stream>>>(Ob, WoT, out, S, D, D);
}